// Round 1
// baseline (18.045 us; speedup 1.0000x reference)
//
#include <hip/hip_runtime.h>

#define MARGIN 0.5f
#define NROWS 4096
#define D 128
#define ROWS_PER_BLOCK 4   // 4 waves/block, 1 wave per row

__global__ __launch_bounds__(256) void mrl_row_kernel(
    const float* __restrict__ logits,
    const int*   __restrict__ labels,
    float* __restrict__ row_mean,
    float* __restrict__ row_valid)
{
    const int wave = threadIdx.x >> 6;      // 0..3
    const int lane = threadIdx.x & 63;      // 0..63
    const int row  = blockIdx.x * ROWS_PER_BLOCK + wave;

    __shared__ float s_l [ROWS_PER_BLOCK][D];
    __shared__ float s_nm[ROWS_PER_BLOCK][D];

    const float* lrow   = logits + (size_t)row * D;
    const int*   labrow = labels + (size_t)row * D;

    // each lane owns 2 consecutive elements -> vectorized, coalesced loads
    const int i0 = lane * 2;
    float2 lv = *reinterpret_cast<const float2*>(lrow + i0);
    int2   bv = *reinterpret_cast<const int2*>(labrow + i0);

    float l0 = lv.x, l1 = lv.y;
    float pm0 = (bv.x > 0)  ? 1.f : 0.f;
    float pm1 = (bv.y > 0)  ? 1.f : 0.f;
    float nm0 = (bv.x == 0) ? 1.f : 0.f;
    float nm1 = (bv.y == 0) ? 1.f : 0.f;

    s_l [wave][i0]     = l0;
    s_l [wave][i0 + 1] = l1;
    s_nm[wave][i0]     = nm0;
    s_nm[wave][i0 + 1] = nm1;
    __syncthreads();

    // acc_i = sum_j neg[j] * relu(l[j] - l[i] + margin)
    float acc0 = 0.f, acc1 = 0.f;
#pragma unroll 8
    for (int j = 0; j < D; ++j) {
        float lj  = s_l [wave][j];   // broadcast read: conflict-free
        float nmj = s_nm[wave][j];
        float t0 = fmaxf(lj - l0 + MARGIN, 0.f);
        float t1 = fmaxf(lj - l1 + MARGIN, 0.f);
        acc0 = fmaf(nmj, t0, acc0);
        acc1 = fmaf(nmj, t1, acc1);
    }

    float rsum = pm0 * acc0 + pm1 * acc1;   // only positives contribute
    float psum = pm0 + pm1;
    float nsum = nm0 + nm1;

    // wave(64)-wide butterfly reduce
    for (int off = 32; off > 0; off >>= 1) {
        rsum += __shfl_xor(rsum, off);
        psum += __shfl_xor(psum, off);
        nsum += __shfl_xor(nsum, off);
    }

    if (lane == 0) {
        float cnt   = psum * nsum;          // npos * nneg
        bool  valid = cnt > 0.f;
        row_mean [row] = valid ? rsum / cnt : 0.f;
        row_valid[row] = valid ? 1.f : 0.f;
    }
}

__global__ __launch_bounds__(256) void mrl_reduce_kernel(
    const float* __restrict__ row_mean,
    const float* __restrict__ row_valid,
    float* __restrict__ out)
{
    float s = 0.f, v = 0.f;
    for (int i = threadIdx.x; i < NROWS; i += 256) {
        s += row_mean[i];
        v += row_valid[i];
    }
    for (int off = 32; off > 0; off >>= 1) {
        s += __shfl_xor(s, off);
        v += __shfl_xor(v, off);
    }
    __shared__ float ss[4], sv[4];
    const int wave = threadIdx.x >> 6;
    const int lane = threadIdx.x & 63;
    if (lane == 0) { ss[wave] = s; sv[wave] = v; }
    __syncthreads();
    if (threadIdx.x == 0) {
        float S = ss[0] + ss[1] + ss[2] + ss[3];
        float V = sv[0] + sv[1] + sv[2] + sv[3];
        out[0] = (V > 0.f) ? S / V : 0.f;
    }
}

extern "C" void kernel_launch(void* const* d_in, const int* in_sizes, int n_in,
                              void* d_out, int out_size, void* d_ws, size_t ws_size,
                              hipStream_t stream) {
    const float* logits = (const float*)d_in[0];
    const int*   labels = (const int*)d_in[1];
    float* out = (float*)d_out;
    float* ws  = (float*)d_ws;           // [0..NROWS): row means, [NROWS..2*NROWS): valid flags

    mrl_row_kernel<<<NROWS / ROWS_PER_BLOCK, 256, 0, stream>>>(logits, labels, ws, ws + NROWS);
    mrl_reduce_kernel<<<1, 256, 0, stream>>>(ws, ws + NROWS, out);
}

// Round 2
// 11.903 us; speedup vs baseline: 1.5160x; 1.5160x over previous
//
#include <hip/hip_runtime.h>

#define MARGIN 0.5f
#define NROWS 4096
#define D 128
#define ROWS_PER_BLOCK 4   // 4 waves/block, 1 wave per row
#define NBLOCKS (NROWS / ROWS_PER_BLOCK)

// Kernel 1: one wave per row.
//  - ballot-compact negative logits into LDS (padded to x4 with -3e38)
//  - ballot-compact positive constants c = MARGIN - l_i into LDS
//  - each lane takes positives p = lane, lane+64, ... and sums
//      sum_j fmax(neg_j + c_p, 0) over float4 broadcast reads
//  - wave-reduce, per-row mean, block partials to ws
__global__ __launch_bounds__(256) void mrl_row_kernel(
    const float* __restrict__ logits,
    const int*   __restrict__ labels,
    float* __restrict__ partial_sum,   // [NBLOCKS]
    float* __restrict__ partial_val)   // [NBLOCKS]
{
    const int wave = threadIdx.x >> 6;
    const int lane = threadIdx.x & 63;
    const int row  = blockIdx.x * ROWS_PER_BLOCK + wave;

    // 132 floats/row: 128 max + up to 4 pad; 528 B stride keeps 16B alignment
    __shared__ float s_neg[ROWS_PER_BLOCK][132];
    __shared__ float s_pos[ROWS_PER_BLOCK][132];
    __shared__ float sb_sum[ROWS_PER_BLOCK];
    __shared__ float sb_val[ROWS_PER_BLOCK];

    const float* lrow   = logits + (size_t)row * D;
    const int*   labrow = labels + (size_t)row * D;

    const int i0 = lane * 2;
    float2 lv = *reinterpret_cast<const float2*>(lrow + i0);
    int2   bv = *reinterpret_cast<const int2*>(labrow + i0);

    const bool n0 = (bv.x == 0), n1 = (bv.y == 0);
    const bool p0 = (bv.x > 0),  p1 = (bv.y > 0);

    const unsigned long long mn0 = __ballot(n0);
    const unsigned long long mn1 = __ballot(n1);
    const unsigned long long mp0 = __ballot(p0);
    const unsigned long long mp1 = __ballot(p1);
    const unsigned long long below = (1ull << lane) - 1ull;

    const int nneg = __popcll(mn0) + __popcll(mn1);
    const int npos = __popcll(mp0) + __popcll(mp1);

    if (n0) s_neg[wave][__popcll(mn0 & below)]                 = lv.x;
    if (n1) s_neg[wave][__popcll(mn0) + __popcll(mn1 & below)] = lv.y;
    if (p0) s_pos[wave][__popcll(mp0 & below)]                 = MARGIN - lv.x;
    if (p1) s_pos[wave][__popcll(mp0) + __popcll(mp1 & below)] = MARGIN - lv.y;

    // pad negs to a multiple of 4 with -BIG so fmax(neg+c,0)==0
    if (lane < 4) s_neg[wave][nneg + lane] = -3.0e38f;

    __syncthreads();

    const int nneg4 = (nneg + 3) >> 2;
    const float4* vp = reinterpret_cast<const float4*>(s_neg[wave]);

    float acc = 0.f;
    for (int p = lane; p < npos; p += 64) {
        const float c = s_pos[wave][p];
        float a = 0.f;
#pragma unroll 2
        for (int q = 0; q < nneg4; ++q) {
            float4 v = vp[q];                 // broadcast read, conflict-free
            a += fmaxf(v.x + c, 0.f);
            a += fmaxf(v.y + c, 0.f);
            a += fmaxf(v.z + c, 0.f);
            a += fmaxf(v.w + c, 0.f);
        }
        acc += a;
    }

    for (int off = 32; off > 0; off >>= 1)
        acc += __shfl_xor(acc, off);

    if (lane == 0) {
        const int cnt = npos * nneg;
        sb_sum[wave] = (cnt > 0) ? acc / (float)cnt : 0.f;
        sb_val[wave] = (cnt > 0) ? 1.f : 0.f;
    }
    __syncthreads();
    if (threadIdx.x == 0) {
        partial_sum[blockIdx.x] = sb_sum[0] + sb_sum[1] + sb_sum[2] + sb_sum[3];
        partial_val[blockIdx.x] = sb_val[0] + sb_val[1] + sb_val[2] + sb_val[3];
    }
}

__global__ __launch_bounds__(256) void mrl_reduce_kernel(
    const float* __restrict__ partial_sum,
    const float* __restrict__ partial_val,
    float* __restrict__ out)
{
    float s = 0.f, v = 0.f;
    for (int i = threadIdx.x; i < NBLOCKS; i += 256) {
        s += partial_sum[i];
        v += partial_val[i];
    }
    for (int off = 32; off > 0; off >>= 1) {
        s += __shfl_xor(s, off);
        v += __shfl_xor(v, off);
    }
    __shared__ float ss[4], sv[4];
    const int wave = threadIdx.x >> 6;
    const int lane = threadIdx.x & 63;
    if (lane == 0) { ss[wave] = s; sv[wave] = v; }
    __syncthreads();
    if (threadIdx.x == 0) {
        float S = ss[0] + ss[1] + ss[2] + ss[3];
        float V = sv[0] + sv[1] + sv[2] + sv[3];
        out[0] = (V > 0.f) ? S / V : 0.f;
    }
}

extern "C" void kernel_launch(void* const* d_in, const int* in_sizes, int n_in,
                              void* d_out, int out_size, void* d_ws, size_t ws_size,
                              hipStream_t stream) {
    const float* logits = (const float*)d_in[0];
    const int*   labels = (const int*)d_in[1];
    float* out = (float*)d_out;
    float* ws  = (float*)d_ws;   // [0..NBLOCKS) partial sums, [NBLOCKS..2*NBLOCKS) valid counts

    mrl_row_kernel<<<NBLOCKS, 256, 0, stream>>>(logits, labels, ws, ws + NBLOCKS);
    mrl_reduce_kernel<<<1, 256, 0, stream>>>(ws, ws + NBLOCKS, out);
}